// Round 3
// baseline (288.845 us; speedup 1.0000x reference)
//
#include <hip/hip_runtime.h>

#define B_ 4
#define C_ 256
#define L_ 4096
#define NG 32
#define CPG 8
#define BL (B_ * L_)               // 16384 token rows
#define QLOG2E 0.09016844f         // C^-0.5 * log2(e), folded into q_w/q_b

typedef __attribute__((ext_vector_type(8))) __bf16 bf16x8;
typedef __attribute__((ext_vector_type(8))) short s16x8;
typedef __attribute__((ext_vector_type(4))) float f32x4;
typedef __attribute__((ext_vector_type(16))) float f32x16;

__device__ __forceinline__ unsigned short f2bf(float f) {
  unsigned int u = __builtin_bit_cast(unsigned int, f);
  u += 0x7fffu + ((u >> 16) & 1u);
  return (unsigned short)(u >> 16);
}
#if __has_builtin(__builtin_amdgcn_exp2f)
#define EXP2F(x) __builtin_amdgcn_exp2f(x)
#else
#define EXP2F(x) exp2f(x)
#endif

// async global->LDS, 16B per lane; dest = ldsbase + lane*16 (wave-uniform base)
__device__ __forceinline__ void gld_lds16(const void* g, void* l) {
  __builtin_amdgcn_global_load_lds(
      (const __attribute__((address_space(1))) unsigned int*)g,
      (__attribute__((address_space(3))) unsigned int*)l, 16, 0, 0);
}

// sum-reduce over each 16-lane group: quad xor1, xor2, then row_ror:4, row_ror:8
__device__ __forceinline__ float red16_add(float x) {
  int i;
  i = __builtin_amdgcn_update_dpp(0, __builtin_bit_cast(int, x), 0xB1, 0xF, 0xF, false);
  x += __builtin_bit_cast(float, i);
  i = __builtin_amdgcn_update_dpp(0, __builtin_bit_cast(int, x), 0x4E, 0xF, 0xF, false);
  x += __builtin_bit_cast(float, i);
  i = __builtin_amdgcn_update_dpp(0, __builtin_bit_cast(int, x), 0x124, 0xF, 0xF, false);
  x += __builtin_bit_cast(float, i);
  i = __builtin_amdgcn_update_dpp(0, __builtin_bit_cast(int, x), 0x128, 0xF, 0xF, false);
  x += __builtin_bit_cast(float, i);
  return x;
}

// ---------------- wcvt: f32 weights -> bf16 (q_w pre-scaled), scaled q bias --------
__global__ __launch_bounds__(256) void wcvt_k(const float* __restrict__ qw,
                                              const float* __restrict__ kw,
                                              const float* __restrict__ vw,
                                              const float* __restrict__ pw,
                                              const float* __restrict__ qb,
                                              unsigned short* __restrict__ wq,
                                              unsigned short* __restrict__ wk,
                                              unsigned short* __restrict__ wv,
                                              unsigned short* __restrict__ wp,
                                              float* __restrict__ qbs) {
  const int m = blockIdx.x >> 5;
  const int blk = blockIdx.x & 31;
  const float* src = (m == 0) ? qw : (m == 1) ? kw : (m == 2) ? vw : pw;
  unsigned short* dst = (m == 0) ? wq : (m == 1) ? wk : (m == 2) ? wv : wp;
  const float sc = (m == 0) ? QLOG2E : 1.0f;
  const int base = (blk * 256 + threadIdx.x) * 8;
  f32x4 a = *(const f32x4*)(src + base);
  f32x4 b = *(const f32x4*)(src + base + 4);
  s16x8 o;
#pragma unroll
  for (int j = 0; j < 4; ++j) {
    o[j] = (short)f2bf(a[j] * sc);
    o[4 + j] = (short)f2bf(b[j] * sc);
  }
  *(s16x8*)(dst + base) = o;
  if (m == 0 && blk == 0) qbs[threadIdx.x] = qb[threadIdx.x] * QLOG2E;
}

// ---------------- GroupNorm: stats per (b, group) ----------------
__global__ __launch_bounds__(256) void gn_stats_k(const float* __restrict__ x,
                                                  float* __restrict__ stats) {
  const int bg = blockIdx.x;
  const float* base = x + (size_t)bg * (CPG * L_);
  const int t = threadIdx.x;
  float s = 0.f, ss = 0.f;
#pragma unroll
  for (int i = 0; i < 32; ++i) {
    f32x4 v = *(const f32x4*)(base + (size_t)(t + i * 256) * 4);
#pragma unroll
    for (int j = 0; j < 4; ++j) { s += v[j]; ss += v[j] * v[j]; }
  }
#pragma unroll
  for (int d = 1; d < 64; d <<= 1) {
    s += __shfl_xor(s, d, 64);
    ss += __shfl_xor(ss, d, 64);
  }
  __shared__ float red[8];
  if ((t & 63) == 0) { red[(t >> 6) * 2] = s; red[(t >> 6) * 2 + 1] = ss; }
  __syncthreads();
  if (t == 0) {
    float S = red[0] + red[2] + red[4] + red[6];
    float SS = red[1] + red[3] + red[5] + red[7];
    const float inv_n = 1.f / (float)(CPG * L_);
    float mean = S * inv_n;
    float var = SS * inv_n - mean * mean;
    stats[bg * 2] = mean;
    stats[bg * 2 + 1] = rsqrtf(var + 1e-6f);
  }
}

// ------------- GroupNorm apply + transpose -> ht[B*L, C] bf16 -------------
__global__ __launch_bounds__(256) void gn_apply_k(const float* __restrict__ x,
                                                  const float* __restrict__ stats,
                                                  const float* __restrict__ gam,
                                                  const float* __restrict__ bet,
                                                  unsigned short* __restrict__ ht) {
  __shared__ unsigned short tile[64 * 256];
  const int blk = blockIdx.x;
  const int b = blk >> 6;
  const int l0 = (blk & 63) * 64;
  const int t = threadIdx.x;
  const int c = t;
  const float mean = stats[(b * NG + (c >> 3)) * 2];
  const float rstd = stats[(b * NG + (c >> 3)) * 2 + 1];
  const float sc = rstd * gam[c];
  const float sb = bet[c] - mean * sc;
  const float* row = x + ((size_t)(b * C_ + c)) * L_ + l0;
#pragma unroll
  for (int v = 0; v < 16; ++v) {
    f32x4 f = *(const f32x4*)(row + v * 4);
#pragma unroll
    for (int j = 0; j < 4; ++j) tile[(v * 4 + j) * 256 + c] = f2bf(f[j] * sc + sb);
  }
  __syncthreads();
#pragma unroll
  for (int i = 0; i < 8; ++i) {
    int id = t + i * 256;
    int l = id >> 5, off = id & 31;
    *(s16x8*)(ht + ((size_t)(b * L_) + l0 + l) * 256 + off * 8) =
        *(const s16x8*)(tile + l * 256 + off * 8);
  }
}

// ------------- GEMM-T: Ct[m,n] = sum_k A[m,k]*W[n,k] + bias[n]  (bf16 out) -------------
__global__ __launch_bounds__(256) void gemm_t_k(const unsigned short* __restrict__ A,
                                                const unsigned short* __restrict__ W,
                                                const float* __restrict__ bias,
                                                unsigned short* __restrict__ Ct) {
  __shared__ unsigned short Al[64 * 256];
  __shared__ unsigned short Wl[64 * 256];
  const int m0 = blockIdx.x * 64;
  const int n0 = blockIdx.y * 64;
  const int t = threadIdx.x;
#pragma unroll
  for (int i = 0; i < 8; ++i) {
    int id = t + i * 256;
    int row = id >> 5, c16 = id & 31;
    int pos = (c16 ^ (row & 7)) * 8;
    *(s16x8*)(Al + row * 256 + pos) =
        *(const s16x8*)(A + (size_t)(m0 + row) * 256 + c16 * 8);
    *(s16x8*)(Wl + row * 256 + pos) =
        *(const s16x8*)(W + (size_t)(n0 + row) * 256 + c16 * 8);
  }
  __syncthreads();
  const int w = t >> 6, lane = t & 63, l15 = lane & 15, q = lane >> 4;
  bf16x8 af[8];
#pragma unroll
  for (int kf = 0; kf < 8; ++kf) {
    int row = w * 16 + l15;
    af[kf] = *(const bf16x8*)(Al + row * 256 + (((kf * 4 + q) ^ (row & 7)) * 8));
  }
  f32x4 acc[4];
#pragma unroll
  for (int nf = 0; nf < 4; ++nf) {
    f32x4 cacc = {0.f, 0.f, 0.f, 0.f};
#pragma unroll
    for (int kf = 0; kf < 8; ++kf) {
      int row = nf * 16 + l15;
      bf16x8 bf = *(const bf16x8*)(Wl + row * 256 + (((kf * 4 + q) ^ (row & 7)) * 8));
      cacc = __builtin_amdgcn_mfma_f32_16x16x32_bf16(af[kf], bf, cacc, 0, 0, 0);
    }
    acc[nf] = cacc;
  }
#pragma unroll
  for (int nf = 0; nf < 4; ++nf) {
    const int n = n0 + nf * 16 + l15;
    const float bs = bias[n];
#pragma unroll
    for (int r = 0; r < 4; ++r) {
      const int m = m0 + w * 16 + q * 4 + r;
      Ct[(size_t)m * 256 + n] = f2bf(acc[nf][r] + bs);
    }
  }
}

// ------------- GEMM-N: out[o,i] = sum_k W[o,k]*X[b*L+i,k] + bias[o] -------------
// MODE 0: bf16 out to swizzled V layout [b][jt(64)][c][jc^(c&7)][8].
// MODE 1: fp32 out + residual x (natural [B,C,L]).
template <int MODE>
__global__ __launch_bounds__(256) void gemm_n_k(const unsigned short* __restrict__ X,
                                                const unsigned short* __restrict__ W,
                                                const float* __restrict__ bias,
                                                const float* __restrict__ xres,
                                                void* __restrict__ outv) {
  __shared__ unsigned short Wl[64 * 256];
  __shared__ unsigned short Xl[64 * 256];
  const int i0 = blockIdx.x * 64;
  const int o0 = blockIdx.y * 64;
  const int b = blockIdx.z;
  const int t = threadIdx.x;
#pragma unroll
  for (int i = 0; i < 8; ++i) {
    int id = t + i * 256;
    int row = id >> 5, c16 = id & 31;
    int pos = (c16 ^ (row & 7)) * 8;
    *(s16x8*)(Wl + row * 256 + pos) =
        *(const s16x8*)(W + (size_t)(o0 + row) * 256 + c16 * 8);
    *(s16x8*)(Xl + row * 256 + pos) =
        *(const s16x8*)(X + ((size_t)(b * L_) + i0 + row) * 256 + c16 * 8);
  }
  __syncthreads();
  const int w = t >> 6, lane = t & 63, l15 = lane & 15, q = lane >> 4;
  bf16x8 af[8];
#pragma unroll
  for (int kf = 0; kf < 8; ++kf) {
    int row = w * 16 + l15;
    af[kf] = *(const bf16x8*)(Wl + row * 256 + (((kf * 4 + q) ^ (row & 7)) * 8));
  }
  f32x4 acc[4];
#pragma unroll
  for (int nf = 0; nf < 4; ++nf) {
    f32x4 cacc = {0.f, 0.f, 0.f, 0.f};
#pragma unroll
    for (int kf = 0; kf < 8; ++kf) {
      int row = nf * 16 + l15;
      bf16x8 bf = *(const bf16x8*)(Xl + row * 256 + (((kf * 4 + q) ^ (row & 7)) * 8));
      cacc = __builtin_amdgcn_mfma_f32_16x16x32_bf16(af[kf], bf, cacc, 0, 0, 0);
    }
    acc[nf] = cacc;
  }
#pragma unroll
  for (int nf = 0; nf < 4; ++nf) {
    const int i = i0 + nf * 16 + l15;
#pragma unroll
    for (int r = 0; r < 4; ++r) {
      const int o = o0 + w * 16 + q * 4 + r;
      float v = acc[nf][r] + bias[o];
      if (MODE == 0) {
        const int jt = i >> 6, jc = (i >> 3) & 7, jj = i & 7;
        ((unsigned short*)outv)[((((size_t)(b * 64 + jt)) * 256 + o) * 8 + (jc ^ (o & 7))) * 8 + jj] =
            f2bf(v);
      } else {
        const size_t idx = ((size_t)(b * C_ + o)) * L_ + i;
        ((float*)outv)[idx] = v + xres[idx];
      }
    }
  }
}

// ------------- Flash attention v3: 32 queries/block, key-split waves -------------
// Qt,Kt: [B*L, C] bf16 rows (Q pre-scaled by QLOG2E); Vg: swizzled tiles.
// No online rescale: p = exp2(s) directly (max |s| ~ 8.5, safe in bf16/f32).
__global__ __launch_bounds__(256, 2) void attn_k(const unsigned short* __restrict__ Qt,
                                                 const unsigned short* __restrict__ Kt,
                                                 const unsigned short* __restrict__ Vg,
                                                 unsigned short* __restrict__ Om) {
  __shared__ unsigned short Kl[64 * 256];   // 32 KB [keyrow][chunk^ (row&7)]
  __shared__ unsigned short Vl[2048 * 8];   // 32 KB [c][jc (swz)][8]
  __shared__ unsigned short Pl[4 * 32 * 24];// per-wave [32 q][16 k] rows padded to 24
  __shared__ float Ls[32];
  const int bid = blockIdx.x;
  const int b = bid >> 7;
  const int i0 = (bid & 127) * 32;
  const int t = threadIdx.x;
  const int w = t >> 6, lane = t & 63;
  const int l15 = lane & 15, q = lane >> 4;
  const int l31 = lane & 31, h = lane >> 5;

  if (t < 32) Ls[t] = 0.f;

  // Q fragments in registers for whole kernel: 2 m-frags x 8 kf
  bf16x8 qf0[8], qf1[8];
  {
    const size_t qr0 = ((size_t)b * L_ + i0 + l15) * 256;
#pragma unroll
    for (int kf = 0; kf < 8; ++kf) {
      qf0[kf] = *(const bf16x8*)(Qt + qr0 + kf * 32 + q * 8);
      qf1[kf] = *(const bf16x8*)(Qt + qr0 + 16 * 256 + kf * 32 + q * 8);
    }
  }
  f32x16 oacc[8];
#pragma unroll
  for (int cf = 0; cf < 8; ++cf)
#pragma unroll
    for (int g = 0; g < 16; ++g) oacc[cf][g] = 0.f;
  float l0[4] = {0.f, 0.f, 0.f, 0.f}, l1[4] = {0.f, 0.f, 0.f, 0.f};

  const unsigned short* kbase = Kt + (size_t)b * L_ * 256;
  const unsigned short* vbase = Vg + (size_t)b * 64 * 2048 * 8;
  unsigned short* Pw = Pl + w * 768;
  const int krow = w * 16 + l15;         // this wave's key row in the 64-key tile

  for (int it = 0; it < 64; ++it) {
    __syncthreads();                     // previous tile fully consumed
    // stage K (32 KB) + V (32 KB) via async DMA; K swizzled at source,
    // V pre-swizzled in global layout -> both linear LDS dests.
    {
      const unsigned short* ksrc = kbase + (size_t)(it * 64) * 256;
      const unsigned short* vsrc = vbase + (size_t)it * 2048 * 8;
#pragma unroll
      for (int i = 0; i < 8; ++i) {
        const int seg = w * 8 + i;
        const int idx = seg * 64 + lane;
        const int row = idx >> 5, c16 = idx & 31;
        gld_lds16(ksrc + (size_t)row * 256 + ((c16 ^ (row & 7)) * 8), Kl + seg * 512);
        gld_lds16(vsrc + (size_t)idx * 8, Vl + seg * 512);
      }
    }
    __syncthreads();                     // drains vmcnt (compiler-inserted)

    // QK^T: 32 queries x this wave's 16 keys
    f32x4 s0 = {0.f, 0.f, 0.f, 0.f}, s1 = {0.f, 0.f, 0.f, 0.f};
    const unsigned short* klrow = Kl + krow * 256;
#pragma unroll
    for (int kf = 0; kf < 8; ++kf) {
      bf16x8 kb = *(const bf16x8*)(klrow + (((kf * 4 + q) ^ (krow & 7)) * 8));
      s0 = __builtin_amdgcn_mfma_f32_16x16x32_bf16(qf0[kf], kb, s0, 0, 0, 0);
      s1 = __builtin_amdgcn_mfma_f32_16x16x32_bf16(qf1[kf], kb, s1, 0, 0, 0);
    }
    // p = exp2(s); accumulate row-sum partials per lane; P -> per-wave LDS
#pragma unroll
    for (int r = 0; r < 4; ++r) {
      float p0 = EXP2F(s0[r]);
      float p1 = EXP2F(s1[r]);
      l0[r] += p0;
      l1[r] += p1;
      Pw[(q * 4 + r) * 24 + l15] = f2bf(p0);
      Pw[(16 + q * 4 + r) * 24 + l15] = f2bf(p1);
    }
    // PV: 32x32x16, k = the wave's 16 keys
    bf16x8 pa = *(const bf16x8*)(Pw + l31 * 24 + h * 8);
#pragma unroll
    for (int cf = 0; cf < 8; ++cf) {
      const int c = cf * 32 + l31;
      bf16x8 vb = *(const bf16x8*)(Vl + (c * 8 + ((w * 2 + h) ^ (c & 7))) * 8);
      oacc[cf] = __builtin_amdgcn_mfma_f32_32x32x16_bf16(pa, vb, oacc[cf], 0, 0, 0);
    }
  }

  // row-sums: reduce per-lane partials over 16-lane groups (VALU DPP), then LDS atomics
#pragma unroll
  for (int r = 0; r < 4; ++r) {
    l0[r] = red16_add(l0[r]);
    l1[r] = red16_add(l1[r]);
  }
  if (l15 == 0) {
#pragma unroll
    for (int r = 0; r < 4; ++r) {
      atomicAdd(&Ls[q * 4 + r], l0[r]);
      atomicAdd(&Ls[16 + q * 4 + r], l1[r]);
    }
  }

  // merge 4 wave partials: waves 0,1 write buf A/B; waves 2,3 add; then combine
  __syncthreads();
  float* bufA = (float*)Kl;
  float* bufB = (float*)Vl;
  {
    float* buf = (w & 1) ? bufB : bufA;
    if (w < 2) {
#pragma unroll
      for (int cf = 0; cf < 8; ++cf)
#pragma unroll
        for (int g = 0; g < 16; ++g) {
          const int row = (g & 3) + 8 * (g >> 2) + 4 * h;
          buf[row * 256 + cf * 32 + l31] = oacc[cf][g];
        }
    }
    __syncthreads();
    if (w >= 2) {
#pragma unroll
      for (int cf = 0; cf < 8; ++cf)
#pragma unroll
        for (int g = 0; g < 16; ++g) {
          const int row = (g & 3) + 8 * (g >> 2) + 4 * h;
          buf[row * 256 + cf * 32 + l31] += oacc[cf][g];
        }
    }
  }
  __syncthreads();
  // normalize + write out 32 rows x 256 c
  {
    const int orow = t >> 3, c0 = (t & 7) * 32;
    const float inv = 1.0f / Ls[orow];
    const float* pA = bufA + orow * 256 + c0;
    const float* pB = bufB + orow * 256 + c0;
    unsigned short* dst = Om + ((size_t)(b * L_) + i0 + orow) * 256 + c0;
#pragma unroll
    for (int u = 0; u < 4; ++u) {
      s16x8 pk;
#pragma unroll
      for (int j = 0; j < 8; ++j)
        pk[j] = (short)f2bf((pA[u * 8 + j] + pB[u * 8 + j]) * inv);
      *(s16x8*)(dst + u * 8) = pk;
    }
  }
}

extern "C" void kernel_launch(void* const* d_in, const int* in_sizes, int n_in,
                              void* d_out, int out_size, void* d_ws, size_t ws_size,
                              hipStream_t stream) {
  const float* x = (const float*)d_in[0];
  const float* norm_g = (const float*)d_in[1];
  const float* norm_b = (const float*)d_in[2];
  const float* q_w = (const float*)d_in[3];
  const float* q_b = (const float*)d_in[4];
  const float* k_w = (const float*)d_in[5];
  const float* k_b = (const float*)d_in[6];
  const float* v_w = (const float*)d_in[7];
  const float* v_b = (const float*)d_in[8];
  const float* p_w = (const float*)d_in[9];
  const float* p_b = (const float*)d_in[10];
  float* out = (float*)d_out;
  (void)in_sizes; (void)n_in; (void)out_size; (void)ws_size;

  char* ws = (char*)d_ws;
  const size_t MB = 1u << 20;
  float* stats = (float*)ws;                              // 1 KB
  float* qbs = (float*)(ws + 1024);                       // 1 KB
  unsigned short* wq = (unsigned short*)(ws + 4096);      // 128 KB each
  unsigned short* wk = wq + 65536;
  unsigned short* wv = wk + 65536;
  unsigned short* wp = wv + 65536;
  unsigned short* ht = (unsigned short*)(ws + 1 * MB);    // 8 MB (later: attn out)
  unsigned short* qt = (unsigned short*)(ws + 9 * MB);    // 8 MB
  unsigned short* kt = (unsigned short*)(ws + 17 * MB);   // 8 MB
  unsigned short* vg = (unsigned short*)(ws + 25 * MB);   // 8 MB swizzled V tiles

  wcvt_k<<<128, 256, 0, stream>>>(q_w, k_w, v_w, p_w, q_b, wq, wk, wv, wp, qbs);
  gn_stats_k<<<B_ * NG, 256, 0, stream>>>(x, stats);
  gn_apply_k<<<B_ * (L_ / 64), 256, 0, stream>>>(x, stats, norm_g, norm_b, ht);
  gemm_t_k<<<dim3((B_ * L_) / 64, C_ / 64), 256, 0, stream>>>(ht, wq, qbs, qt);
  gemm_t_k<<<dim3((B_ * L_) / 64, C_ / 64), 256, 0, stream>>>(ht, wk, k_b, kt);
  gemm_n_k<0><<<dim3(L_ / 64, C_ / 64, B_), 256, 0, stream>>>(ht, wv, v_b, nullptr, vg);
  attn_k<<<B_ * (L_ / 32), 256, 0, stream>>>(qt, kt, vg, ht);
  gemm_n_k<1><<<dim3(L_ / 64, C_ / 64, B_), 256, 0, stream>>>(ht, wp, p_b, x, out);
}

// Round 4
// 209.485 us; speedup vs baseline: 1.3788x; 1.3788x over previous
//
#include <hip/hip_runtime.h>

#define B_ 4
#define C_ 256
#define L_ 4096
#define NG 32
#define CPG 8
#define BL (B_ * L_)               // 16384 token rows
#define KPART 4
#define KEYS_PP (L_ / KPART)       // 1024 keys per partition
#define QLOG2E 0.09016844f         // C^-0.5 * log2(e), folded into q_w/q_b

typedef __attribute__((ext_vector_type(8))) __bf16 bf16x8;
typedef __attribute__((ext_vector_type(8))) short s16x8;
typedef __attribute__((ext_vector_type(4))) float f32x4;
typedef __attribute__((ext_vector_type(16))) float f32x16;

__device__ __forceinline__ unsigned short f2bf(float f) {
  unsigned int u = __builtin_bit_cast(unsigned int, f);
  u += 0x7fffu + ((u >> 16) & 1u);
  return (unsigned short)(u >> 16);
}
__device__ __forceinline__ float bf2f(unsigned short u) {
  unsigned int v = ((unsigned int)u) << 16;
  return __builtin_bit_cast(float, v);
}
#if __has_builtin(__builtin_amdgcn_exp2f)
#define EXP2F(x) __builtin_amdgcn_exp2f(x)
#else
#define EXP2F(x) exp2f(x)
#endif

// async global->LDS, 16B/lane; dest = ldsbase + lane*16 (wave-uniform base)
__device__ __forceinline__ void gld_lds16(const void* g, void* l) {
  __builtin_amdgcn_global_load_lds(
      (const __attribute__((address_space(1))) unsigned int*)g,
      (__attribute__((address_space(3))) unsigned int*)l, 16, 0, 0);
}

// sum-reduce over each 16-lane group via DPP
__device__ __forceinline__ float red16_add(float x) {
  int i;
  i = __builtin_amdgcn_update_dpp(0, __builtin_bit_cast(int, x), 0xB1, 0xF, 0xF, false);
  x += __builtin_bit_cast(float, i);
  i = __builtin_amdgcn_update_dpp(0, __builtin_bit_cast(int, x), 0x4E, 0xF, 0xF, false);
  x += __builtin_bit_cast(float, i);
  i = __builtin_amdgcn_update_dpp(0, __builtin_bit_cast(int, x), 0x124, 0xF, 0xF, false);
  x += __builtin_bit_cast(float, i);
  i = __builtin_amdgcn_update_dpp(0, __builtin_bit_cast(int, x), 0x128, 0xF, 0xF, false);
  x += __builtin_bit_cast(float, i);
  return x;
}

// ------- init: weight cvt (blocks 0..127) + GN stats (blocks 128..255) -------
__global__ __launch_bounds__(256) void init_k(const float* __restrict__ qw,
                                              const float* __restrict__ kw,
                                              const float* __restrict__ vw,
                                              const float* __restrict__ pw,
                                              const float* __restrict__ qb,
                                              const float* __restrict__ x,
                                              unsigned short* __restrict__ wq,
                                              unsigned short* __restrict__ wk,
                                              unsigned short* __restrict__ wv,
                                              unsigned short* __restrict__ wp,
                                              float* __restrict__ qbs,
                                              float* __restrict__ stats) {
  const int bid = blockIdx.x;
  const int t = threadIdx.x;
  if (bid < 128) {
    const int m = bid >> 5;
    const int blk = bid & 31;
    const float* src = (m == 0) ? qw : (m == 1) ? kw : (m == 2) ? vw : pw;
    unsigned short* dst = (m == 0) ? wq : (m == 1) ? wk : (m == 2) ? wv : wp;
    const float sc = (m == 0) ? QLOG2E : 1.0f;
    const int base = (blk * 256 + t) * 8;
    f32x4 a = *(const f32x4*)(src + base);
    f32x4 b = *(const f32x4*)(src + base + 4);
    s16x8 o;
#pragma unroll
    for (int j = 0; j < 4; ++j) {
      o[j] = (short)f2bf(a[j] * sc);
      o[4 + j] = (short)f2bf(b[j] * sc);
    }
    *(s16x8*)(dst + base) = o;
    if (m == 0 && blk == 0) qbs[t] = qb[t] * QLOG2E;
  } else {
    const int bg = bid - 128;
    const float* base = x + (size_t)bg * (CPG * L_);
    float s = 0.f, ss = 0.f;
#pragma unroll
    for (int i = 0; i < 32; ++i) {
      f32x4 v = *(const f32x4*)(base + (size_t)(t + i * 256) * 4);
#pragma unroll
      for (int j = 0; j < 4; ++j) { s += v[j]; ss += v[j] * v[j]; }
    }
#pragma unroll
    for (int d = 1; d < 64; d <<= 1) {
      s += __shfl_xor(s, d, 64);
      ss += __shfl_xor(ss, d, 64);
    }
    __shared__ float red[8];
    if ((t & 63) == 0) { red[(t >> 6) * 2] = s; red[(t >> 6) * 2 + 1] = ss; }
    __syncthreads();
    if (t == 0) {
      float S = red[0] + red[2] + red[4] + red[6];
      float SS = red[1] + red[3] + red[5] + red[7];
      const float inv_n = 1.f / (float)(CPG * L_);
      float mean = S * inv_n;
      float var = SS * inv_n - mean * mean;
      stats[bg * 2] = mean;
      stats[bg * 2 + 1] = rsqrtf(var + 1e-6f);
    }
  }
}

// ------------- GroupNorm apply + transpose -> ht[B*L, C] bf16 -------------
__global__ __launch_bounds__(256) void gn_apply_k(const float* __restrict__ x,
                                                  const float* __restrict__ stats,
                                                  const float* __restrict__ gam,
                                                  const float* __restrict__ bet,
                                                  unsigned short* __restrict__ ht) {
  __shared__ unsigned short tile[64 * 256];
  const int blk = blockIdx.x;
  const int b = blk >> 6;
  const int l0 = (blk & 63) * 64;
  const int t = threadIdx.x;
  const int c = t;
  const float mean = stats[(b * NG + (c >> 3)) * 2];
  const float rstd = stats[(b * NG + (c >> 3)) * 2 + 1];
  const float sc = rstd * gam[c];
  const float sb = bet[c] - mean * sc;
  const float* row = x + ((size_t)(b * C_ + c)) * L_ + l0;
#pragma unroll
  for (int v = 0; v < 16; ++v) {
    f32x4 f = *(const f32x4*)(row + v * 4);
#pragma unroll
    for (int j = 0; j < 4; ++j) tile[(v * 4 + j) * 256 + c] = f2bf(f[j] * sc + sb);
  }
  __syncthreads();
#pragma unroll
  for (int i = 0; i < 8; ++i) {
    int id = t + i * 256;
    int l = id >> 5, off = id & 31;
    *(s16x8*)(ht + ((size_t)(b * L_) + l0 + l) * 256 + off * 8) =
        *(const s16x8*)(tile + l * 256 + off * 8);
  }
}

// ------------- GEMM-T: Ct[m,n] = sum_k A[m,k]*W[n,k] + bias[n]  (bf16 out) -------------
__global__ __launch_bounds__(256) void gemm_t_k(const unsigned short* __restrict__ A,
                                                const unsigned short* __restrict__ W,
                                                const float* __restrict__ bias,
                                                unsigned short* __restrict__ Ct) {
  __shared__ unsigned short Al[64 * 256];
  __shared__ unsigned short Wl[64 * 256];
  const int m0 = blockIdx.x * 64;
  const int n0 = blockIdx.y * 64;
  const int t = threadIdx.x;
  const int w = t >> 6, lane = t & 63, l15 = lane & 15, q = lane >> 4;
#pragma unroll
  for (int i = 0; i < 8; ++i) {
    const int seg = w * 8 + i;
    const int idx = seg * 64 + lane;
    const int row = idx >> 5, c16 = idx & 31;
    gld_lds16(A + (size_t)(m0 + row) * 256 + ((c16 ^ (row & 7)) * 8), Al + seg * 512);
    gld_lds16(W + (size_t)(n0 + row) * 256 + ((c16 ^ (row & 7)) * 8), Wl + seg * 512);
  }
  __syncthreads();
  bf16x8 af[8];
#pragma unroll
  for (int kf = 0; kf < 8; ++kf) {
    int row = w * 16 + l15;
    af[kf] = *(const bf16x8*)(Al + row * 256 + (((kf * 4 + q) ^ (row & 7)) * 8));
  }
  f32x4 acc[4];
#pragma unroll
  for (int nf = 0; nf < 4; ++nf) {
    f32x4 cacc = {0.f, 0.f, 0.f, 0.f};
#pragma unroll
    for (int kf = 0; kf < 8; ++kf) {
      int row = nf * 16 + l15;
      bf16x8 bf = *(const bf16x8*)(Wl + row * 256 + (((kf * 4 + q) ^ (row & 7)) * 8));
      cacc = __builtin_amdgcn_mfma_f32_16x16x32_bf16(af[kf], bf, cacc, 0, 0, 0);
    }
    acc[nf] = cacc;
  }
#pragma unroll
  for (int nf = 0; nf < 4; ++nf) {
    const int n = n0 + nf * 16 + l15;
    const float bs = bias[n];
#pragma unroll
    for (int r = 0; r < 4; ++r) {
      const int m = m0 + w * 16 + q * 4 + r;
      Ct[(size_t)m * 256 + n] = f2bf(acc[nf][r] + bs);
    }
  }
}

// ------------- GEMM-N: out[o,i] = sum_k W[o,k]*X[b*L+i,k] + bias[o] -------------
// MODE 0: bf16 out to attn V-tile layout [b][jt(128 tiles of 32 keys)][c][qc swz][8].
// MODE 1: fp32 out + residual x (natural [B,C,L]).
template <int MODE>
__global__ __launch_bounds__(256) void gemm_n_k(const unsigned short* __restrict__ X,
                                                const unsigned short* __restrict__ W,
                                                const float* __restrict__ bias,
                                                const float* __restrict__ xres,
                                                void* __restrict__ outv) {
  __shared__ unsigned short Wl[64 * 256];
  __shared__ unsigned short Xl[64 * 256];
  const int i0 = blockIdx.x * 64;
  const int o0 = blockIdx.y * 64;
  const int b = blockIdx.z;
  const int t = threadIdx.x;
  const int w = t >> 6, lane = t & 63, l15 = lane & 15, q = lane >> 4;
#pragma unroll
  for (int i = 0; i < 8; ++i) {
    const int seg = w * 8 + i;
    const int idx = seg * 64 + lane;
    const int row = idx >> 5, c16 = idx & 31;
    gld_lds16(W + (size_t)(o0 + row) * 256 + ((c16 ^ (row & 7)) * 8), Wl + seg * 512);
    gld_lds16(X + ((size_t)(b * L_) + i0 + row) * 256 + ((c16 ^ (row & 7)) * 8),
              Xl + seg * 512);
  }
  __syncthreads();
  bf16x8 af[8];
#pragma unroll
  for (int kf = 0; kf < 8; ++kf) {
    int row = w * 16 + l15;
    af[kf] = *(const bf16x8*)(Wl + row * 256 + (((kf * 4 + q) ^ (row & 7)) * 8));
  }
  f32x4 acc[4];
#pragma unroll
  for (int nf = 0; nf < 4; ++nf) {
    f32x4 cacc = {0.f, 0.f, 0.f, 0.f};
#pragma unroll
    for (int kf = 0; kf < 8; ++kf) {
      int row = nf * 16 + l15;
      bf16x8 bf = *(const bf16x8*)(Xl + row * 256 + (((kf * 4 + q) ^ (row & 7)) * 8));
      cacc = __builtin_amdgcn_mfma_f32_16x16x32_bf16(af[kf], bf, cacc, 0, 0, 0);
    }
    acc[nf] = cacc;
  }
#pragma unroll
  for (int nf = 0; nf < 4; ++nf) {
    const int i = i0 + nf * 16 + l15;
#pragma unroll
    for (int r = 0; r < 4; ++r) {
      const int o = o0 + w * 16 + q * 4 + r;
      float v = acc[nf][r] + bias[o];
      if (MODE == 0) {
        const int jt = i >> 5, jj = i & 31;
        const int qc = jj >> 3, pos = jj & 7;
        ((unsigned short*)outv)[((size_t)(b * 128 + jt)) * 8192 + o * 32 +
                                ((qc ^ ((o >> 1) & 3)) * 8) + pos] = f2bf(v);
      } else {
        const size_t idx = ((size_t)(b * C_ + o)) * L_ + i;
        ((float*)outv)[idx] = v + xres[idx];
      }
    }
  }
}

// ------------- Flash attention v4: 128 q/block, query-split waves, KPART=4 -------------
// Qt,Kt: [B*L, C] bf16 rows (Q pre-scaled by QLOG2E); Vg: 32-key swizzled tiles.
// p = exp2(s) directly; partial O (unnormalized) + row-sums l per partition.
__global__ __launch_bounds__(256, 2) void attn_k(const unsigned short* __restrict__ Qt,
                                                 const unsigned short* __restrict__ Kt,
                                                 const unsigned short* __restrict__ Vg,
                                                 unsigned short* __restrict__ op01,
                                                 unsigned short* __restrict__ op23,
                                                 float* __restrict__ ml) {
  __shared__ unsigned short Kl[32 * 256];    // 16 KB [keyrow][chunk ^ (row&7)]
  __shared__ unsigned short Vl[256 * 32];    // 16 KB [c][qc swz][8]
  __shared__ unsigned short Pl[4 * 32 * 40]; // per-wave [32 q][32 k] rows padded to 40
  const int bid = blockIdx.x;
  const int g = bid & 15;                    // co-locates (b,part) per XCD
  const int b = g >> 2, part = g & 3;
  const int qi = bid >> 4;                   // 0..31 q-tile within batch
  const int t = threadIdx.x;
  const int w = t >> 6, lane = t & 63;
  const int l15 = lane & 15, q = lane >> 4;
  const int l31 = lane & 31, h = lane >> 5;

  const int qrow0 = b * L_ + qi * 128 + w * 32;  // wave's first query row (global)
  bf16x8 qf[2][8];
#pragma unroll
  for (int mi = 0; mi < 2; ++mi)
#pragma unroll
    for (int kf = 0; kf < 8; ++kf)
      qf[mi][kf] =
          *(const bf16x8*)(Qt + ((size_t)(qrow0 + mi * 16 + l15)) * 256 + kf * 32 + q * 8);

  f32x16 oacc[8];
#pragma unroll
  for (int nf = 0; nf < 8; ++nf)
#pragma unroll
    for (int gg = 0; gg < 16; ++gg) oacc[nf][gg] = 0.f;
  float ls0[4] = {0.f, 0.f, 0.f, 0.f}, ls1[4] = {0.f, 0.f, 0.f, 0.f};

  const unsigned short* kbase = Kt + ((size_t)(b * L_ + part * KEYS_PP)) * 256;
  const unsigned short* vbase = Vg + ((size_t)(b * 128 + part * 32)) * 8192;
  unsigned short* Pw = Pl + w * 1280;

  for (int it = 0; it < KEYS_PP / 32; ++it) {
    __syncthreads();
    {
      const unsigned short* ksrc = kbase + (size_t)(it * 32) * 256;
      const unsigned short* vsrc = vbase + (size_t)it * 8192;
#pragma unroll
      for (int i = 0; i < 4; ++i) {
        const int seg = w * 4 + i;
        const int idx = seg * 64 + lane;
        const int row = idx >> 5, c16 = idx & 31;
        gld_lds16(ksrc + (size_t)row * 256 + ((c16 ^ (row & 7)) * 8), Kl + seg * 512);
        gld_lds16(vsrc + (size_t)idx * 8, Vl + seg * 512);
      }
    }
    __syncthreads();

    // QK^T: wave's 32 queries x 32 keys
    f32x4 s00 = {0.f, 0.f, 0.f, 0.f}, s01 = s00, s10 = s00, s11 = s00;
#pragma unroll
    for (int kf = 0; kf < 8; ++kf) {
      const int ch = ((kf * 4 + q) ^ (l15 & 7)) * 8;
      bf16x8 kb0 = *(const bf16x8*)(Kl + l15 * 256 + ch);
      bf16x8 kb1 = *(const bf16x8*)(Kl + (16 + l15) * 256 + ch);
      s00 = __builtin_amdgcn_mfma_f32_16x16x32_bf16(qf[0][kf], kb0, s00, 0, 0, 0);
      s01 = __builtin_amdgcn_mfma_f32_16x16x32_bf16(qf[0][kf], kb1, s01, 0, 0, 0);
      s10 = __builtin_amdgcn_mfma_f32_16x16x32_bf16(qf[1][kf], kb0, s10, 0, 0, 0);
      s11 = __builtin_amdgcn_mfma_f32_16x16x32_bf16(qf[1][kf], kb1, s11, 0, 0, 0);
    }
#pragma unroll
    for (int r = 0; r < 4; ++r) {
      float p00 = EXP2F(s00[r]), p01 = EXP2F(s01[r]);
      float p10 = EXP2F(s10[r]), p11 = EXP2F(s11[r]);
      ls0[r] += p00 + p01;
      ls1[r] += p10 + p11;
      Pw[(q * 4 + r) * 40 + l15] = f2bf(p00);
      Pw[(q * 4 + r) * 40 + 16 + l15] = f2bf(p01);
      Pw[(16 + q * 4 + r) * 40 + l15] = f2bf(p10);
      Pw[(16 + q * 4 + r) * 40 + 16 + l15] = f2bf(p11);
    }
    // PV: 32x32x16, two 16-key halves
    bf16x8 pa0 = *(const bf16x8*)(Pw + l31 * 40 + h * 8);
    bf16x8 pa1 = *(const bf16x8*)(Pw + l31 * 40 + 16 + h * 8);
#pragma unroll
    for (int nf = 0; nf < 8; ++nf) {
      const int c = nf * 32 + l31;
      bf16x8 v0 = *(const bf16x8*)(Vl + c * 32 + ((h ^ ((c >> 1) & 3)) * 8));
      bf16x8 v1 = *(const bf16x8*)(Vl + c * 32 + (((2 + h) ^ ((c >> 1) & 3)) * 8));
      oacc[nf] = __builtin_amdgcn_mfma_f32_32x32x16_bf16(pa0, v0, oacc[nf], 0, 0, 0);
      oacc[nf] = __builtin_amdgcn_mfma_f32_32x32x16_bf16(pa1, v1, oacc[nf], 0, 0, 0);
    }
  }

  // write partial O (32x32 C-layout: col=l31, row=(g&3)+8*(g>>2)+4*h)
  unsigned short* opb = (part < 2) ? op01 + (size_t)part * BL * 256
                                   : op23 + (size_t)(part - 2) * BL * 256;
#pragma unroll
  for (int nf = 0; nf < 8; ++nf)
#pragma unroll
    for (int gg = 0; gg < 16; ++gg) {
      const int row = (gg & 3) + 8 * (gg >> 2) + 4 * h;
      opb[(size_t)(qrow0 + row) * 256 + nf * 32 + l31] = f2bf(oacc[nf][gg]);
    }
  // row-sums
#pragma unroll
  for (int r = 0; r < 4; ++r) {
    ls0[r] = red16_add(ls0[r]);
    ls1[r] = red16_add(ls1[r]);
  }
  if (l15 == 0) {
    float* mlp = ml + (size_t)part * BL;
#pragma unroll
    for (int r = 0; r < 4; ++r) {
      mlp[qrow0 + q * 4 + r] = ls0[r];
      mlp[qrow0 + 16 + q * 4 + r] = ls1[r];
    }
  }
}

// ------------- merge 4 partials -> Om [B*L, C] bf16 -------------
__global__ __launch_bounds__(256) void merge_k(const unsigned short* __restrict__ op01,
                                               const unsigned short* __restrict__ op23,
                                               const float* __restrict__ ml,
                                               unsigned short* __restrict__ Om) {
  const int row = blockIdx.x * 8 + (threadIdx.x >> 5);
  const int c8 = threadIdx.x & 31;
  const float inv = 1.0f / (ml[row] + ml[BL + row] + ml[2 * BL + row] + ml[3 * BL + row]);
  const size_t off = (size_t)row * 256 + c8 * 8;
  s16x8 v0 = *(const s16x8*)(op01 + off);
  s16x8 v1 = *(const s16x8*)(op01 + (size_t)BL * 256 + off);
  s16x8 v2 = *(const s16x8*)(op23 + off);
  s16x8 v3 = *(const s16x8*)(op23 + (size_t)BL * 256 + off);
  s16x8 o;
#pragma unroll
  for (int j = 0; j < 8; ++j)
    o[j] = (short)f2bf((bf2f((unsigned short)v0[j]) + bf2f((unsigned short)v1[j]) +
                        bf2f((unsigned short)v2[j]) + bf2f((unsigned short)v3[j])) *
                       inv);
  *(s16x8*)(Om + off) = o;
}

extern "C" void kernel_launch(void* const* d_in, const int* in_sizes, int n_in,
                              void* d_out, int out_size, void* d_ws, size_t ws_size,
                              hipStream_t stream) {
  const float* x = (const float*)d_in[0];
  const float* norm_g = (const float*)d_in[1];
  const float* norm_b = (const float*)d_in[2];
  const float* q_w = (const float*)d_in[3];
  const float* q_b = (const float*)d_in[4];
  const float* k_w = (const float*)d_in[5];
  const float* k_b = (const float*)d_in[6];
  const float* v_w = (const float*)d_in[7];
  const float* v_b = (const float*)d_in[8];
  const float* p_w = (const float*)d_in[9];
  const float* p_b = (const float*)d_in[10];
  float* out = (float*)d_out;
  (void)in_sizes; (void)n_in; (void)out_size; (void)ws_size;

  char* ws = (char*)d_ws;
  const size_t MB = 1u << 20;
  float* stats = (float*)ws;                              // 1 KB
  float* qbs = (float*)(ws + 1024);                       // 1 KB
  unsigned short* wq = (unsigned short*)(ws + 4096);      // 128 KB each
  unsigned short* wk = wq + 65536;
  unsigned short* wv = wk + 65536;
  unsigned short* wp = wv + 65536;
  unsigned short* ht = (unsigned short*)(ws + 1 * MB);    // 8 MB (later: merged O)
  unsigned short* qt = (unsigned short*)(ws + 9 * MB);    // 8 MB
  unsigned short* kt = (unsigned short*)(ws + 17 * MB);   // 8 MB
  unsigned short* vg = (unsigned short*)(ws + 25 * MB);   // 8 MB V tiles
  unsigned short* op23 = (unsigned short*)(ws + 33 * MB); // 16.78 MB (parts 2,3)
  float* ml = (float*)(ws + 50 * MB);                     // 256 KB
  unsigned short* op01 = (unsigned short*)d_out;          // parts 0,1 (16.78 MB)

  init_k<<<256, 256, 0, stream>>>(q_w, k_w, v_w, p_w, q_b, x, wq, wk, wv, wp, qbs, stats);
  gn_apply_k<<<B_ * (L_ / 64), 256, 0, stream>>>(x, stats, norm_g, norm_b, ht);
  gemm_t_k<<<dim3((B_ * L_) / 64, C_ / 64), 256, 0, stream>>>(ht, wq, qbs, qt);
  gemm_t_k<<<dim3((B_ * L_) / 64, C_ / 64), 256, 0, stream>>>(ht, wk, k_b, kt);
  gemm_n_k<0><<<dim3(L_ / 64, C_ / 64, B_), 256, 0, stream>>>(ht, wv, v_b, nullptr, vg);
  attn_k<<<512, 256, 0, stream>>>(qt, kt, vg, op01, op23, ml);
  merge_k<<<BL / 8, 256, 0, stream>>>(op01, op23, ml, ht);
  gemm_n_k<1><<<dim3(L_ / 64, C_ / 64, B_), 256, 0, stream>>>(ht, wp, p_b, x, out);
}